// Round 1
// baseline (73.838 us; speedup 1.0000x reference)
//
#include <hip/hip_runtime.h>
#include <stdint.h>

// Contrastive loss: B=16384 samples, C=1000 classes, D=128 dims, fp32 in,
// scalar fp32 out.  dist = f2 + c2 - 2*cross; loss = sum(relu(1-dist) masked)/B.
#define B_N 16384
#define C_N 1000
#define D_N 128
#define MARGIN 1.0f

typedef __attribute__((ext_vector_type(8))) short short8;  // 8 bf16 (4 VGPRs)
typedef __attribute__((ext_vector_type(4))) float f32x4;   // MFMA accumulator

// fp32 -> bf16 round-to-nearest-even, as raw bits in a short.
__device__ __forceinline__ short f2bf(float f) {
    union { float f; uint32_t u; } v; v.f = f;
    uint32_t u = v.u;
    uint32_t r = (u + 0x7FFFu + ((u >> 16) & 1u)) >> 16;
    return (short)r;
}

__global__ void zero_out_kernel(float* out) { out[0] = 0.0f; }

// One block = 128x128 output tile. 256 threads = 4 waves (2x2), each wave owns
// a 64x64 sub-tile = 4x4 fragments of 16x16, K=128 staged once (full depth).
__global__ __launch_bounds__(256) void closs_kernel(
    const float* __restrict__ feat, const int* __restrict__ tgt,
    const float* __restrict__ cls, float* __restrict__ out)
{
    // Pad leading dim to 136 shorts (272 B): row stride is 16B-aligned for
    // ds_read_b128 and bank groups (4*r mod 32) make fragment reads ~2-way
    // (free) instead of 8-way.
    __shared__ short As[128][136];
    __shared__ short Bs[128][136];
    __shared__ float f2s[128];
    __shared__ float c2s[128];

    const int tid  = threadIdx.x;
    const int brow = blockIdx.y;   // 0..127  (row tile: features)
    const int bcol = blockIdx.x;   // 0..7    (col tile: classes, last partial)

    // ---- stage A (features) and B (classes) tiles, fp32 -> bf16 ----
    // 128x128 fp32 each = 4096 float4; 256 threads x 16 float4.
    #pragma unroll
    for (int i = 0; i < 16; ++i) {
        const int idx = tid + i * 256;   // float4 index 0..4095
        const int r   = idx >> 5;        // 32 float4 per row
        const int c4  = idx & 31;
        // A
        const float4 av = *reinterpret_cast<const float4*>(
            feat + ((size_t)(brow * 128 + r) * D_N + c4 * 4));
        uint2 ap;
        ap.x = ((uint32_t)(uint16_t)f2bf(av.x)) | ((uint32_t)(uint16_t)f2bf(av.y) << 16);
        ap.y = ((uint32_t)(uint16_t)f2bf(av.z)) | ((uint32_t)(uint16_t)f2bf(av.w) << 16);
        *reinterpret_cast<uint2*>(&As[r][c4 * 4]) = ap;
        // B (zero-fill rows past C=1000; masked again in epilogue)
        const int j = bcol * 128 + r;
        float4 bv = make_float4(0.f, 0.f, 0.f, 0.f);
        if (j < C_N)
            bv = *reinterpret_cast<const float4*>(cls + ((size_t)j * D_N + c4 * 4));
        uint2 bp;
        bp.x = ((uint32_t)(uint16_t)f2bf(bv.x)) | ((uint32_t)(uint16_t)f2bf(bv.y) << 16);
        bp.y = ((uint32_t)(uint16_t)f2bf(bv.z)) | ((uint32_t)(uint16_t)f2bf(bv.w) << 16);
        *reinterpret_cast<uint2*>(&Bs[r][c4 * 4]) = bp;
    }
    __syncthreads();

    // ---- f2 / c2 from the bf16-staged tiles (consistent with the GEMM) ----
    {
        const int r = tid & 127;
        const short (*S)[136] = (tid < 128) ? As : Bs;
        float s = 0.f;
        #pragma unroll
        for (int k8 = 0; k8 < 16; ++k8) {
            short8 v = *reinterpret_cast<const short8*>(&S[r][k8 * 8]);
            #pragma unroll
            for (int e = 0; e < 8; ++e) {
                union { uint32_t u; float f; } c; c.u = ((uint32_t)(uint16_t)v[e]) << 16;
                s += c.f * c.f;
            }
        }
        if (tid < 128) f2s[r] = s; else c2s[r] = s;
    }
    __syncthreads();

    // ---- MFMA: cross = A · B^T (both operands K-contiguous row-major) ----
    const int wave = tid >> 6;
    const int lane = tid & 63;
    const int wr   = (wave >> 1) * 64;  // wave row base in tile
    const int wc   = (wave & 1) * 64;   // wave col base in tile
    const int l15  = lane & 15;
    const int kg   = lane >> 4;         // k-group 0..3

    f32x4 acc[4][4];
    #pragma unroll
    for (int m = 0; m < 4; ++m)
        #pragma unroll
        for (int n = 0; n < 4; ++n)
            acc[m][n] = (f32x4){0.f, 0.f, 0.f, 0.f};

    #pragma unroll
    for (int kk = 0; kk < 4; ++kk) {    // 4 K-steps of 32
        const int k0 = kk * 32 + kg * 8;
        short8 a[4], b[4];
        #pragma unroll
        for (int m = 0; m < 4; ++m)
            a[m] = *reinterpret_cast<const short8*>(&As[wr + m * 16 + l15][k0]);
        #pragma unroll
        for (int n = 0; n < 4; ++n)
            b[n] = *reinterpret_cast<const short8*>(&Bs[wc + n * 16 + l15][k0]);
        #pragma unroll
        for (int m = 0; m < 4; ++m)
            #pragma unroll
            for (int n = 0; n < 4; ++n)
                acc[m][n] = __builtin_amdgcn_mfma_f32_16x16x32_bf16(
                    a[m], b[n], acc[m][n], 0, 0, 0);
    }

    // ---- epilogue: hinge + masks, reduce, one atomic per wave ----
    // C/D layout (verified m89): col = lane&15, row = (lane>>4)*4 + reg.
    float sum = 0.f;
    const int row_l0 = wr + kg * 4;
    const int col_l0 = wc + l15;
    #pragma unroll
    for (int m = 0; m < 4; ++m) {
        #pragma unroll
        for (int r = 0; r < 4; ++r) {
            const int row_l = row_l0 + m * 16 + r;
            const int grow  = brow * 128 + row_l;
            const int t     = tgt[grow];
            const float f2  = f2s[row_l];
            #pragma unroll
            for (int n = 0; n < 4; ++n) {
                const int col_l = col_l0 + n * 16;
                const int gcol  = bcol * 128 + col_l;
                const float dist = f2 + c2s[col_l] - 2.0f * acc[m][n][r];
                float h = fmaxf(0.0f, MARGIN - dist);
                if (gcol >= C_N || gcol == t) h = 0.0f;
                sum += h;
            }
        }
    }
    sum *= (1.0f / 16384.0f);
    #pragma unroll
    for (int off = 32; off; off >>= 1) sum += __shfl_down(sum, off);
    if (lane == 0) atomicAdd(out, sum);
}

extern "C" void kernel_launch(void* const* d_in, const int* in_sizes, int n_in,
                              void* d_out, int out_size, void* d_ws, size_t ws_size,
                              hipStream_t stream) {
    const float* feat = (const float*)d_in[0];
    const int*   tgt  = (const int*)d_in[1];
    const float* cls  = (const float*)d_in[2];
    float*       out  = (float*)d_out;

    zero_out_kernel<<<1, 1, 0, stream>>>(out);
    dim3 grid(8, 128);   // x: col tiles (ceil(1000/128)=8), y: row tiles (128)
    closs_kernel<<<grid, 256, 0, stream>>>(feat, tgt, cls, out);
}